// Round 4
// baseline (283.405 us; speedup 1.0000x reference)
//
#include <hip/hip_runtime.h>
#include <math.h>

#define NGRID 343
#define NPATH 20

// ---------------- compile-time Clifford tables (Cl(3,0), blade order:
// 1, e1, e2, e3, e12, e13, e23, e123) ----------------
struct Tab {
  int prod_idx[8][8];
  int prod_sgn[8][8];
  int pid[4][4][4];
  int grade[8];
  int kk_idx[8][8];
  int kk_sgn[8][8];
};

constexpr Tab make_tab() {
  Tab t{};
  int mask[8]  = {0,1,2,4,3,5,6,7};
  int idxof[8] = {0,1,2,4,3,5,6,7};
  for (int k = 0; k < 8; ++k) {
    int g = 0;
    for (int b = 0; b < 3; ++b) g += (mask[k] >> b) & 1;
    t.grade[k] = g;
  }
  for (int k = 0; k < 8; ++k)
    for (int m = 0; m < 8; ++m) {
      int A = mask[k], B = mask[m];
      t.prod_idx[k][m] = idxof[A ^ B];
      int c = 0;
      for (int i = 0; i < 3; ++i)
        if ((B >> i) & 1)
          for (int j = i + 1; j < 3; ++j)
            if ((A >> j) & 1) c++;
      t.prod_sgn[k][m] = (c & 1) ? -1 : 1;
    }
  int pc = 0;
  for (int a = 0; a < 4; ++a)
    for (int b = 0; b < 4; ++b)
      for (int c = 0; c < 4; ++c) {
        bool ok = false;
        for (int k = 0; k < 8; ++k)
          for (int m = 0; m < 8; ++m)
            if (t.grade[k] == a && t.grade[m] == c &&
                t.grade[t.prod_idx[k][m]] == b)
              ok = true;
        t.pid[a][b][c] = ok ? pc++ : NPATH;
      }
  for (int l = 0; l < 8; ++l)
    for (int m = 0; m < 8; ++m)
      for (int k = 0; k < 8; ++k)
        if (t.prod_idx[k][m] == l) {
          t.kk_idx[l][m] = k;
          t.kk_sgn[l][m] = t.prod_sgn[k][m];
        }
  return t;
}
constexpr Tab TB = make_tab();

__device__ __forceinline__ int gradeOf(int b) {
  return (b == 0) ? 0 : (b < 4) ? 1 : (b < 7) ? 2 : 3;
}

// ---------------- workspace layout (floats) ----------------
// lin0_t [4][33][64]     @ 0        (8448)    ([g][ch][hh])
// gps_t  [4][64][64][20] @ 8448     (327680)  ([l][i][o][p])
// outW_t [64][4][1024]   @ 336128   (262144)  ([i][g][oc]) lane-coalesced
// k_ws   [343][1024][8]  @ 598272   (2809856) ([n][oc][b])
// h_buf  [343][64][8]    @ 3408128  (175616)  ([n][i][b])
#define OFF_LIN0T 0
#define OFF_GPST  8448
#define OFF_OUTWT 336128
#define OFF_KWS   598272
#define OFF_HBUF  3408128

// ---------------- kernel 0: weight transpose ----------------
__global__ void ccs_prep_kernel(const float* __restrict__ lin0_W,
                                const float* __restrict__ gps_w,
                                const float* __restrict__ out_W,
                                float* __restrict__ ws) {
  const int TOT = 8448 + 327680 + 262144;
  for (int d = blockIdx.x * blockDim.x + threadIdx.x; d < TOT;
       d += gridDim.x * blockDim.x) {
    float v;
    if (d < 8448) {
      int hh = d & 63, ch = (d >> 6) % 33, g = (d >> 6) / 33;
      v = lin0_W[(g * 64 + hh) * 33 + ch];
    } else if (d < OFF_OUTWT) {
      int idx = d - OFF_GPST;
      int p = idx % 20, r = idx / 20;
      int o = r & 63, i = (r >> 6) & 63, l = r >> 12;
      v = gps_w[(((size_t)l * 64 + o) * 64 + i) * 20 + p];
    } else {
      int idx = d - OFF_OUTWT;
      int oc = idx & 1023, g = (idx >> 10) & 3, i = idx >> 12;
      v = out_W[(g * 1024 + oc) * 64 + i];
    }
    ws[d] = v;
  }
}

// ---------------- kernel 1: per-grid-point network -> h features ----------
__global__ __launch_bounds__(256)
void ccs_net_kernel(const float* __restrict__ condition,
                    const float* __restrict__ rel_pos_sigma,
                    const float* __restrict__ lin0_b,
                    const float* __restrict__ act0_a,
                    const float* __restrict__ act0_b,
                    const float* __restrict__ lins_W,
                    const float* __restrict__ lins_b,
                    const float* __restrict__ acts_a,
                    const float* __restrict__ acts_b,
                    const float* __restrict__ ws,
                    float* __restrict__ hbuf) {
  const float* lin0t = ws + OFF_LIN0T;
  const float* gpst  = ws + OFF_GPST;

  __shared__ __align__(16) float xb[264];    // [ch][b]
  __shared__ __align__(16) float F0[512];    // blade-major [b][64]
  __shared__ __align__(16) float F1[512];
  __shared__ __align__(16) float part[2048]; // [j][isub][o]

  const int n = blockIdx.x;
  const int tid = threadIdx.x;
  const int iz = n % 7, iy = (n / 7) % 7, ix = n / 49;
  const float px = (float)ix - 3.f, py = (float)iy - 3.f, pz = (float)iz - 3.f;
  const float q = px * px + py * py + pz * pz;
  const float sig = rel_pos_sigma[0];
  const float scal = expf(-q / (2.f * sig * sig));

  for (int t = tid; t < 264; t += 256) {  // 264 > 256: must stride
    int ch = t >> 3, b = t & 7;
    float v;
    if (ch == 0)
      v = (b == 0) ? scal : (b == 1) ? px : (b == 2) ? py : (b == 3) ? pz : 0.f;
    else
      v = condition[(ch - 1) * 8 + b];
    xb[t] = v;
  }
  __syncthreads();

  const int hh = tid & 63;
  const int brow = tid >> 6;

  // ---- lin0: xb -> F0 (blade-major) ----
  #pragma unroll
  for (int rep = 0; rep < 2; ++rep) {
    int b = brow + 4 * rep;
    int g = gradeOf(b);
    float acc = (b == 0) ? lin0_b[hh] : 0.f;
    const float* wrow = lin0t + g * (33 * 64) + hh;
    #pragma unroll
    for (int ch = 0; ch < 33; ++ch)
      acc = fmaf(wrow[ch * 64], xb[ch * 8 + b], acc);
    F0[b * 64 + hh] = acc;
  }
  __syncthreads();

  auto silu = [&](const float* src, float* dst, const float* aa,
                  const float* ab) {
    #pragma unroll
    for (int rep = 0; rep < 2; ++rep) {
      int b = brow + 4 * rep;
      int g = gradeOf(b);
      int s0 = (g == 0) ? 0 : (g == 1) ? 1 : (g == 2) ? 4 : 7;
      int cnt = (g == 0 || g == 3) ? 1 : 3;
      float qg = 0.f;
      for (int u = 0; u < cnt; ++u) {
        float v = src[(s0 + u) * 64 + hh];
        qg = fmaf(v, v, qg);
      }
      float z = fmaf(aa[hh * 4 + g], qg, ab[hh * 4 + g]);
      float gate = 1.f / (1.f + expf(-z));
      dst[b * 64 + hh] = src[b * 64 + hh] * gate;
    }
  };

  auto lin = [&](const float* src, float* dst, const float* wl,
                 const float* bias) {
    #pragma unroll
    for (int rep = 0; rep < 2; ++rep) {
      int b = brow + 4 * rep;
      int g = gradeOf(b);
      float acc = (b == 0) ? bias[hh] : 0.f;
      const float4* wr = (const float4*)(wl + ((size_t)g * 64 + hh) * 64);
      #pragma unroll
      for (int u = 0; u < 16; ++u) {
        float4 w = wr[u];
        float4 s = *(const float4*)(src + b * 64 + u * 4);  // wave-uniform
        acc = fmaf(w.x, s.x, acc);
        acc = fmaf(w.y, s.y, acc);
        acc = fmaf(w.z, s.z, acc);
        acc = fmaf(w.w, s.w, acc);
      }
      dst[b * 64 + hh] = acc;
    }
  };

  auto gp = [&](const float* src, float* dst, const float* wl, bool imaj) {
    const int o = tid & 63;
    const int isub = tid >> 6;  // 0..3, 16 i each
    float facc[8];
    #pragma unroll
    for (int j = 0; j < 8; ++j) facc[j] = 0.f;
    const float4* wb = (const float4*)(wl + (size_t)((isub * 16) * 64 + o) * 20);
    #pragma unroll 4
    for (int it = 0; it < 16; ++it) {
      const int i = isub * 16 + it;
      float4 w4[5];
      #pragma unroll
      for (int u = 0; u < 5; ++u) w4[u] = wb[it * 320 + u];
      float x8[8];
      #pragma unroll
      for (int b = 0; b < 8; ++b) x8[b] = src[b * 64 + i];  // broadcast
      const float* wp = (const float*)w4;
      #pragma unroll
      for (int k = 0; k < 8; ++k) {
        const int p = TB.pid[TB.grade[k]][0][TB.grade[k]];
        float tp = x8[k] * x8[k];
        facc[0] = fmaf(TB.prod_sgn[k][k] > 0 ? tp : -tp, wp[p], facc[0]);
      }
      #pragma unroll
      for (int k = 0; k < 8; ++k) {
        #pragma unroll
        for (int m = k + 1; m < 8; ++m) {
          const int j  = TB.prod_idx[k][m];
          const int p1 = TB.pid[TB.grade[k]][TB.grade[j]][TB.grade[m]];
          const int p2 = TB.pid[TB.grade[m]][TB.grade[j]][TB.grade[k]];
          const float w1 = (TB.prod_sgn[k][m] > 0) ? wp[p1] : -wp[p1];
          const float w2 = (TB.prod_sgn[m][k] > 0) ? wp[p2] : -wp[p2];
          facc[j] = fmaf(x8[k] * x8[m], w1 + w2, facc[j]);
        }
      }
    }
    #pragma unroll
    for (int j = 0; j < 8; ++j) part[(j * 4 + isub) * 64 + o] = facc[j];
    __syncthreads();
    #pragma unroll
    for (int rep = 0; rep < 2; ++rep) {
      int idx = tid + rep * 256;
      int j2 = idx >> 6, o2 = idx & 63;
      float s = part[(j2 * 4 + 0) * 64 + o2] + part[(j2 * 4 + 1) * 64 + o2] +
                part[(j2 * 4 + 2) * 64 + o2] + part[(j2 * 4 + 3) * 64 + o2];
      s *= 0.125f;
      if (imaj)
        dst[o2 * 8 + j2] = s;
      else
        dst[j2 * 64 + o2] = s;
    }
    __syncthreads();
  };

  // ---- layer 0 ----
  silu(F0, F1, act0_a, act0_b);
  __syncthreads();
  gp(F1, F0, gpst + 0, false);

  // ---- layers 1..3 ----
  float* f = F0;
  float* g_ = F1;
  #pragma unroll 1
  for (int l = 0; l < 3; ++l) {
    lin(f, g_, lins_W + (size_t)l * 16384, lins_b + l * 64);
    __syncthreads();
    silu(g_, f, acts_a + l * 256, acts_b + l * 256);
    __syncthreads();
    gp(f, g_, gpst + (size_t)(l + 1) * 81920, l == 2);
    float* t = f; f = g_; g_ = t;
  }

  // f now holds h in i-major [i][b]; write coalesced to hbuf[n][i][b]
  if (tid < 128)
    ((float4*)(hbuf + (size_t)n * 512))[tid] = ((const float4*)f)[tid];
}

// ---------------- kernel 2: output linear + shell -> kws -----------------
// grid (4 oc-chunks, 43 n-chunks of 8); out_W amortized across 8 n.
__global__ __launch_bounds__(256)
void ccs_out_kernel(const float* __restrict__ out_b,
                    const float* __restrict__ shell_sigma,
                    const float* __restrict__ ws,
                    const float* __restrict__ hbuf,
                    float* __restrict__ kws) {
  const float* outwt = ws + OFF_OUTWT;
  const int tid = threadIdx.x;
  const int oc = blockIdx.x * 256 + tid;
  const int n0 = blockIdx.y * 8;
  const int nn = (n0 + 8 <= NGRID) ? 8 : (NGRID - n0);

  __shared__ __align__(16) float sh[8 * 512];  // [n'][i*8+b]
  for (int idx = tid; idx < nn * 128; idx += 256)
    ((float4*)sh)[idx] = ((const float4*)(hbuf + (size_t)n0 * 512))[idx];
  __syncthreads();

  float acc[8][8];
  const float bias = out_b[oc];
  #pragma unroll
  for (int np = 0; np < 8; ++np) {
    #pragma unroll
    for (int b = 0; b < 8; ++b) acc[np][b] = 0.f;
    acc[np][0] = bias;
  }

  #pragma unroll 4
  for (int i = 0; i < 64; ++i) {
    const float w0 = outwt[(i * 4 + 0) * 1024 + oc];  // lane-coalesced
    const float w1 = outwt[(i * 4 + 1) * 1024 + oc];
    const float w2 = outwt[(i * 4 + 2) * 1024 + oc];
    const float w3 = outwt[(i * 4 + 3) * 1024 + oc];
    #pragma unroll
    for (int np = 0; np < 8; ++np) {
      const float* h = sh + np * 512 + i * 8;  // wave-uniform broadcast
      float4 h0 = ((const float4*)h)[0];
      float4 h1 = ((const float4*)h)[1];
      acc[np][0] = fmaf(w0, h0.x, acc[np][0]);
      acc[np][1] = fmaf(w1, h0.y, acc[np][1]);
      acc[np][2] = fmaf(w1, h0.z, acc[np][2]);
      acc[np][3] = fmaf(w1, h0.w, acc[np][3]);
      acc[np][4] = fmaf(w2, h1.x, acc[np][4]);
      acc[np][5] = fmaf(w2, h1.y, acc[np][5]);
      acc[np][6] = fmaf(w2, h1.z, acc[np][6]);
      acc[np][7] = fmaf(w3, h1.w, acc[np][7]);
    }
  }

  const float FACTOR = 1.0f / sqrtf(343.0f);
  float4 s0 = ((const float4*)(shell_sigma + oc * 8))[0];
  float4 s1 = ((const float4*)(shell_sigma + oc * 8))[1];
  for (int np = 0; np < nn; ++np) {
    const int n = n0 + np;
    const int iz = n % 7, iy = (n / 7) % 7, ix = n / 49;
    const float px = (float)ix - 3.f, py = (float)iy - 3.f,
                pz = (float)iz - 3.f;
    const float q = px * px + py * py + pz * pz;
    float o8[8];
    o8[0] = acc[np][0] * expf(-q / (s0.x * s0.x)) * FACTOR;
    o8[1] = acc[np][1] * expf(-q / (s0.y * s0.y)) * FACTOR;
    o8[2] = acc[np][2] * expf(-q / (s0.z * s0.z)) * FACTOR;
    o8[3] = acc[np][3] * expf(-q / (s0.w * s0.w)) * FACTOR;
    o8[4] = acc[np][4] * expf(-q / (s1.x * s1.x)) * FACTOR;
    o8[5] = acc[np][5] * expf(-q / (s1.y * s1.y)) * FACTOR;
    o8[6] = acc[np][6] * expf(-q / (s1.z * s1.z)) * FACTOR;
    o8[7] = acc[np][7] * expf(-q / (s1.w * s1.w)) * FACTOR;
    float4* dst = (float4*)(kws + ((size_t)n * 1024 + oc) * 8);
    dst[0] = make_float4(o8[0], o8[1], o8[2], o8[3]);
    dst[1] = make_float4(o8[4], o8[5], o8[6], o8[7]);
  }
}

// ---------------- kernel 3: Cayley expansion to output ----------------
__global__ __launch_bounds__(256)
void ccs_expand_kernel(const float* __restrict__ cayley_w,
                       const float* __restrict__ kws,
                       float* __restrict__ out) {
  const int oi = blockIdx.x;  // o*32 + i
  const int o = oi >> 5, i = oi & 31;
  const int l0 = blockIdx.y * 4;
  const int tid = threadIdx.x;
  __shared__ float sk[343 * 9];  // stride 9 -> conflict-free

  for (int idx = tid; idx < 686; idx += 256) {
    int nn = idx >> 1, h = (idx & 1) * 4;
    float4 v = *(const float4*)(kws + ((size_t)nn * 1024 + oi) * 8 + h);
    float* s = sk + nn * 9 + h;
    s[0] = v.x; s[1] = v.y; s[2] = v.z; s[3] = v.w;
  }
  float cw[20];
  #pragma unroll
  for (int p = 0; p < 20; ++p) cw[p] = cayley_w[oi * 20 + p];
  __syncthreads();

  #pragma unroll
  for (int dl = 0; dl < 4; ++dl) {
    const int l = l0 + dl;
    #pragma unroll
    for (int m = 0; m < 8; ++m) {
      const int kk = TB.kk_idx[l][m];
      const int p = TB.pid[TB.grade[kk]][TB.grade[l]][TB.grade[m]];
      const float wv = (TB.kk_sgn[l][m] > 0) ? cw[p] : -cw[p];
      float* orow = out + ((size_t)((o * 8 + l) * 256 + i * 8 + m)) * 343;
      for (int c = tid; c < 343; c += 256) orow[c] = sk[c * 9 + kk] * wv;
    }
  }
}

extern "C" void kernel_launch(void* const* d_in, const int* in_sizes, int n_in,
                              void* d_out, int out_size, void* d_ws,
                              size_t ws_size, hipStream_t stream) {
  const float* condition     = (const float*)d_in[0];
  const float* rel_pos_sigma = (const float*)d_in[1];
  const float* cayley_w      = (const float*)d_in[2];
  const float* lin0_W        = (const float*)d_in[3];
  const float* lin0_b        = (const float*)d_in[4];
  const float* act0_a        = (const float*)d_in[5];
  const float* act0_b        = (const float*)d_in[6];
  const float* gps_w         = (const float*)d_in[7];
  const float* lins_W        = (const float*)d_in[8];
  const float* lins_b        = (const float*)d_in[9];
  const float* acts_a        = (const float*)d_in[10];
  const float* acts_b        = (const float*)d_in[11];
  const float* out_W         = (const float*)d_in[12];
  const float* out_b         = (const float*)d_in[13];
  const float* shell_sigma   = (const float*)d_in[14];

  float* ws = (float*)d_ws;
  float* kws = ws + OFF_KWS;
  float* hbuf = ws + OFF_HBUF;
  float* out = (float*)d_out;

  ccs_prep_kernel<<<dim3(640), dim3(256), 0, stream>>>(lin0_W, gps_w, out_W,
                                                       ws);
  ccs_net_kernel<<<dim3(343), dim3(256), 0, stream>>>(
      condition, rel_pos_sigma, lin0_b, act0_a, act0_b, lins_W, lins_b, acts_a,
      acts_b, ws, hbuf);
  ccs_out_kernel<<<dim3(4, 43), dim3(256), 0, stream>>>(out_b, shell_sigma, ws,
                                                        hbuf, kws);
  ccs_expand_kernel<<<dim3(1024, 2), dim3(256), 0, stream>>>(cayley_w, kws,
                                                             out);
}

// Round 5
// 225.018 us; speedup vs baseline: 1.2595x; 1.2595x over previous
//
#include <hip/hip_runtime.h>
#include <math.h>

#define NGRID 343
#define NPATH 20

// ---------------- compile-time Clifford tables (Cl(3,0), blade order:
// 1, e1, e2, e3, e12, e13, e23, e123) ----------------
struct Tab {
  int prod_idx[8][8];
  int prod_sgn[8][8];
  int pid[4][4][4];
  int grade[8];
  int kk_idx[8][8];
  int kk_sgn[8][8];
};

constexpr Tab make_tab() {
  Tab t{};
  int mask[8]  = {0,1,2,4,3,5,6,7};
  int idxof[8] = {0,1,2,4,3,5,6,7};
  for (int k = 0; k < 8; ++k) {
    int g = 0;
    for (int b = 0; b < 3; ++b) g += (mask[k] >> b) & 1;
    t.grade[k] = g;
  }
  for (int k = 0; k < 8; ++k)
    for (int m = 0; m < 8; ++m) {
      int A = mask[k], B = mask[m];
      t.prod_idx[k][m] = idxof[A ^ B];
      int c = 0;
      for (int i = 0; i < 3; ++i)
        if ((B >> i) & 1)
          for (int j = i + 1; j < 3; ++j)
            if ((A >> j) & 1) c++;
      t.prod_sgn[k][m] = (c & 1) ? -1 : 1;
    }
  int pc = 0;
  for (int a = 0; a < 4; ++a)
    for (int b = 0; b < 4; ++b)
      for (int c = 0; c < 4; ++c) {
        bool ok = false;
        for (int k = 0; k < 8; ++k)
          for (int m = 0; m < 8; ++m)
            if (t.grade[k] == a && t.grade[m] == c &&
                t.grade[t.prod_idx[k][m]] == b)
              ok = true;
        t.pid[a][b][c] = ok ? pc++ : NPATH;
      }
  for (int l = 0; l < 8; ++l)
    for (int m = 0; m < 8; ++m)
      for (int k = 0; k < 8; ++k)
        if (t.prod_idx[k][m] == l) {
          t.kk_idx[l][m] = k;
          t.kk_sgn[l][m] = t.prod_sgn[k][m];
        }
  return t;
}
constexpr Tab TB = make_tab();

__device__ __forceinline__ int gradeOf(int b) {
  return (b == 0) ? 0 : (b < 4) ? 1 : (b < 7) ? 2 : 3;
}

// ---------------- workspace layout (floats) ----------------
// lin0_t [4][33][64]     @ 0        (8448)    ([g][ch][hh])
// gps_t  [4][64][64][20] @ 8448     (327680)  ([l][i][o][p])
// outW_t [64][4][1024]   @ 336128   (262144)  ([i][g][oc]) lane-coalesced
// k_ws   [343][1024][8]  @ 598272   (2809856) ([n][oc][b])
// h_buf  [343][64][8]    @ 3408128  (175616)  ([n][i][b])
#define OFF_LIN0T 0
#define OFF_GPST  8448
#define OFF_OUTWT 336128
#define OFF_KWS   598272
#define OFF_HBUF  3408128

// ---------------- kernel 0: weight transpose ----------------
__global__ void ccs_prep_kernel(const float* __restrict__ lin0_W,
                                const float* __restrict__ gps_w,
                                const float* __restrict__ out_W,
                                float* __restrict__ ws) {
  const int TOT = 8448 + 327680 + 262144;
  for (int d = blockIdx.x * blockDim.x + threadIdx.x; d < TOT;
       d += gridDim.x * blockDim.x) {
    float v;
    if (d < 8448) {
      int hh = d & 63, ch = (d >> 6) % 33, g = (d >> 6) / 33;
      v = lin0_W[(g * 64 + hh) * 33 + ch];
    } else if (d < OFF_OUTWT) {
      int idx = d - OFF_GPST;
      int p = idx % 20, r = idx / 20;
      int o = r & 63, i = (r >> 6) & 63, l = r >> 12;
      v = gps_w[(((size_t)l * 64 + o) * 64 + i) * 20 + p];
    } else {
      int idx = d - OFF_OUTWT;
      int oc = idx & 1023, g = (idx >> 10) & 3, i = idx >> 12;
      v = out_W[(g * 1024 + oc) * 64 + i];
    }
    ws[d] = v;
  }
}

// ---------------- kernel 1: per-grid-point network -> h features ----------
__global__ __launch_bounds__(256)
void ccs_net_kernel(const float* __restrict__ condition,
                    const float* __restrict__ rel_pos_sigma,
                    const float* __restrict__ lin0_b,
                    const float* __restrict__ act0_a,
                    const float* __restrict__ act0_b,
                    const float* __restrict__ lins_W,
                    const float* __restrict__ lins_b,
                    const float* __restrict__ acts_a,
                    const float* __restrict__ acts_b,
                    const float* __restrict__ ws,
                    float* __restrict__ hbuf) {
  const float* lin0t = ws + OFF_LIN0T;
  const float* gpst  = ws + OFF_GPST;

  __shared__ __align__(16) float xb[264];    // [ch][b]
  __shared__ __align__(16) float F0[512];    // blade-major [b][64]
  __shared__ __align__(16) float F1[512];
  __shared__ __align__(16) float part[2048]; // [j][isub][o]

  const int n = blockIdx.x;
  const int tid = threadIdx.x;
  const int iz = n % 7, iy = (n / 7) % 7, ix = n / 49;
  const float px = (float)ix - 3.f, py = (float)iy - 3.f, pz = (float)iz - 3.f;
  const float q = px * px + py * py + pz * pz;
  const float sig = rel_pos_sigma[0];
  const float scal = expf(-q / (2.f * sig * sig));

  for (int t = tid; t < 264; t += 256) {  // 264 > 256: must stride
    int ch = t >> 3, b = t & 7;
    float v;
    if (ch == 0)
      v = (b == 0) ? scal : (b == 1) ? px : (b == 2) ? py : (b == 3) ? pz : 0.f;
    else
      v = condition[(ch - 1) * 8 + b];
    xb[t] = v;
  }
  __syncthreads();

  const int hh = tid & 63;
  const int brow = tid >> 6;

  // ---- lin0: xb -> F0 (blade-major) ----
  #pragma unroll
  for (int rep = 0; rep < 2; ++rep) {
    int b = brow + 4 * rep;
    int g = gradeOf(b);
    float acc = (b == 0) ? lin0_b[hh] : 0.f;
    const float* wrow = lin0t + g * (33 * 64) + hh;
    #pragma unroll
    for (int ch = 0; ch < 33; ++ch)
      acc = fmaf(wrow[ch * 64], xb[ch * 8 + b], acc);
    F0[b * 64 + hh] = acc;
  }
  __syncthreads();

  auto silu = [&](const float* src, float* dst, const float* aa,
                  const float* ab) {
    #pragma unroll
    for (int rep = 0; rep < 2; ++rep) {
      int b = brow + 4 * rep;
      int g = gradeOf(b);
      int s0 = (g == 0) ? 0 : (g == 1) ? 1 : (g == 2) ? 4 : 7;
      int cnt = (g == 0 || g == 3) ? 1 : 3;
      float qg = 0.f;
      for (int u = 0; u < cnt; ++u) {
        float v = src[(s0 + u) * 64 + hh];
        qg = fmaf(v, v, qg);
      }
      float z = fmaf(aa[hh * 4 + g], qg, ab[hh * 4 + g]);
      float gate = 1.f / (1.f + expf(-z));
      dst[b * 64 + hh] = src[b * 64 + hh] * gate;
    }
  };

  auto lin = [&](const float* src, float* dst, const float* wl,
                 const float* bias) {
    #pragma unroll
    for (int rep = 0; rep < 2; ++rep) {
      int b = brow + 4 * rep;
      int g = gradeOf(b);
      float acc = (b == 0) ? bias[hh] : 0.f;
      const float4* wr = (const float4*)(wl + ((size_t)g * 64 + hh) * 64);
      #pragma unroll
      for (int u = 0; u < 16; ++u) {
        float4 w = wr[u];
        float4 s = *(const float4*)(src + b * 64 + u * 4);  // wave-uniform
        acc = fmaf(w.x, s.x, acc);
        acc = fmaf(w.y, s.y, acc);
        acc = fmaf(w.z, s.z, acc);
        acc = fmaf(w.w, s.w, acc);
      }
      dst[b * 64 + hh] = acc;
    }
  };

  auto gp = [&](const float* src, float* dst, const float* wl, bool imaj) {
    const int o = tid & 63;
    const int isub = tid >> 6;  // 0..3, 16 i each
    float facc[8];
    #pragma unroll
    for (int j = 0; j < 8; ++j) facc[j] = 0.f;
    const float4* wb = (const float4*)(wl + (size_t)((isub * 16) * 64 + o) * 20);
    #pragma unroll 4
    for (int it = 0; it < 16; ++it) {
      const int i = isub * 16 + it;
      float4 w4[5];
      #pragma unroll
      for (int u = 0; u < 5; ++u) w4[u] = wb[it * 320 + u];
      float x8[8];
      #pragma unroll
      for (int b = 0; b < 8; ++b) x8[b] = src[b * 64 + i];  // broadcast
      const float* wp = (const float*)w4;
      #pragma unroll
      for (int k = 0; k < 8; ++k) {
        const int p = TB.pid[TB.grade[k]][0][TB.grade[k]];
        float tp = x8[k] * x8[k];
        facc[0] = fmaf(TB.prod_sgn[k][k] > 0 ? tp : -tp, wp[p], facc[0]);
      }
      #pragma unroll
      for (int k = 0; k < 8; ++k) {
        #pragma unroll
        for (int m = k + 1; m < 8; ++m) {
          const int j  = TB.prod_idx[k][m];
          const int p1 = TB.pid[TB.grade[k]][TB.grade[j]][TB.grade[m]];
          const int p2 = TB.pid[TB.grade[m]][TB.grade[j]][TB.grade[k]];
          const float w1 = (TB.prod_sgn[k][m] > 0) ? wp[p1] : -wp[p1];
          const float w2 = (TB.prod_sgn[m][k] > 0) ? wp[p2] : -wp[p2];
          facc[j] = fmaf(x8[k] * x8[m], w1 + w2, facc[j]);
        }
      }
    }
    #pragma unroll
    for (int j = 0; j < 8; ++j) part[(j * 4 + isub) * 64 + o] = facc[j];
    __syncthreads();
    #pragma unroll
    for (int rep = 0; rep < 2; ++rep) {
      int idx = tid + rep * 256;
      int j2 = idx >> 6, o2 = idx & 63;
      float s = part[(j2 * 4 + 0) * 64 + o2] + part[(j2 * 4 + 1) * 64 + o2] +
                part[(j2 * 4 + 2) * 64 + o2] + part[(j2 * 4 + 3) * 64 + o2];
      s *= 0.125f;
      if (imaj)
        dst[o2 * 8 + j2] = s;
      else
        dst[j2 * 64 + o2] = s;
    }
    __syncthreads();
  };

  // ---- layer 0 ----
  silu(F0, F1, act0_a, act0_b);
  __syncthreads();
  gp(F1, F0, gpst + 0, false);

  // ---- layers 1..3 ----
  float* f = F0;
  float* g_ = F1;
  #pragma unroll 1
  for (int l = 0; l < 3; ++l) {
    lin(f, g_, lins_W + (size_t)l * 16384, lins_b + l * 64);
    __syncthreads();
    silu(g_, f, acts_a + l * 256, acts_b + l * 256);
    __syncthreads();
    gp(f, g_, gpst + (size_t)(l + 1) * 81920, l == 2);
    float* t = f; f = g_; g_ = t;
  }

  // f now holds h in i-major [i][b]; write coalesced to hbuf[n][i][b]
  if (tid < 128)
    ((float4*)(hbuf + (size_t)n * 512))[tid] = ((const float4*)f)[tid];
}

// ---------------- kernel 2: output linear + shell -> kws -----------------
// grid (4 oc-chunks, 86 n-chunks of 4). NOTE: np loop must be statically
// unrolled with compile-time indices — a runtime-bounded loop over acc[np][..]
// forces the accumulators to scratch (round-4 regression: VGPR=52, 2x WRITE).
__global__ __launch_bounds__(256)
void ccs_out_kernel(const float* __restrict__ out_b,
                    const float* __restrict__ shell_sigma,
                    const float* __restrict__ ws,
                    const float* __restrict__ hbuf,
                    float* __restrict__ kws) {
  const float* outwt = ws + OFF_OUTWT;
  const int tid = threadIdx.x;
  const int oc = blockIdx.x * 256 + tid;
  const int n0 = blockIdx.y * 4;
  const int nn = (n0 + 4 <= NGRID) ? 4 : (NGRID - n0);

  __shared__ __align__(16) float sh[4 * 512];  // [n'][i*8+b]
  for (int idx = tid; idx < nn * 128; idx += 256)
    ((float4*)sh)[idx] = ((const float4*)(hbuf + (size_t)n0 * 512))[idx];
  __syncthreads();

  float acc[4][8];
  const float bias = out_b[oc];
  #pragma unroll
  for (int np = 0; np < 4; ++np) {
    #pragma unroll
    for (int b = 0; b < 8; ++b) acc[np][b] = 0.f;
    acc[np][0] = bias;
  }

  #pragma unroll 4
  for (int i = 0; i < 64; ++i) {
    const float w0 = outwt[(i * 4 + 0) * 1024 + oc];  // lane-coalesced
    const float w1 = outwt[(i * 4 + 1) * 1024 + oc];
    const float w2 = outwt[(i * 4 + 2) * 1024 + oc];
    const float w3 = outwt[(i * 4 + 3) * 1024 + oc];
    #pragma unroll
    for (int np = 0; np < 4; ++np) {
      const float* h = sh + np * 512 + i * 8;  // wave-uniform broadcast
      float4 h0 = ((const float4*)h)[0];
      float4 h1 = ((const float4*)h)[1];
      acc[np][0] = fmaf(w0, h0.x, acc[np][0]);
      acc[np][1] = fmaf(w1, h0.y, acc[np][1]);
      acc[np][2] = fmaf(w1, h0.z, acc[np][2]);
      acc[np][3] = fmaf(w1, h0.w, acc[np][3]);
      acc[np][4] = fmaf(w2, h1.x, acc[np][4]);
      acc[np][5] = fmaf(w2, h1.y, acc[np][5]);
      acc[np][6] = fmaf(w2, h1.z, acc[np][6]);
      acc[np][7] = fmaf(w3, h1.w, acc[np][7]);
    }
  }

  const float FACTOR = 1.0f / sqrtf(343.0f);
  float4 s0 = ((const float4*)(shell_sigma + oc * 8))[0];
  float4 s1 = ((const float4*)(shell_sigma + oc * 8))[1];
  #pragma unroll
  for (int np = 0; np < 4; ++np) {  // static unroll: acc indices constant
    if (np < nn) {
      const int n = n0 + np;
      const int iz = n % 7, iy = (n / 7) % 7, ix = n / 49;
      const float px = (float)ix - 3.f, py = (float)iy - 3.f,
                  pz = (float)iz - 3.f;
      const float q = px * px + py * py + pz * pz;
      float o8[8];
      o8[0] = acc[np][0] * expf(-q / (s0.x * s0.x)) * FACTOR;
      o8[1] = acc[np][1] * expf(-q / (s0.y * s0.y)) * FACTOR;
      o8[2] = acc[np][2] * expf(-q / (s0.z * s0.z)) * FACTOR;
      o8[3] = acc[np][3] * expf(-q / (s0.w * s0.w)) * FACTOR;
      o8[4] = acc[np][4] * expf(-q / (s1.x * s1.x)) * FACTOR;
      o8[5] = acc[np][5] * expf(-q / (s1.y * s1.y)) * FACTOR;
      o8[6] = acc[np][6] * expf(-q / (s1.z * s1.z)) * FACTOR;
      o8[7] = acc[np][7] * expf(-q / (s1.w * s1.w)) * FACTOR;
      float4* dst = (float4*)(kws + ((size_t)n * 1024 + oc) * 8);
      dst[0] = make_float4(o8[0], o8[1], o8[2], o8[3]);
      dst[1] = make_float4(o8[4], o8[5], o8[6], o8[7]);
    }
  }
}

// ---------------- kernel 3: Cayley expansion to output ----------------
__global__ __launch_bounds__(256)
void ccs_expand_kernel(const float* __restrict__ cayley_w,
                       const float* __restrict__ kws,
                       float* __restrict__ out) {
  const int oi = blockIdx.x;  // o*32 + i
  const int o = oi >> 5, i = oi & 31;
  const int l0 = blockIdx.y * 4;
  const int tid = threadIdx.x;
  __shared__ float sk[343 * 9];  // stride 9 -> conflict-free

  for (int idx = tid; idx < 686; idx += 256) {
    int nn = idx >> 1, h = (idx & 1) * 4;
    float4 v = *(const float4*)(kws + ((size_t)nn * 1024 + oi) * 8 + h);
    float* s = sk + nn * 9 + h;
    s[0] = v.x; s[1] = v.y; s[2] = v.z; s[3] = v.w;
  }
  float cw[20];
  #pragma unroll
  for (int p = 0; p < 20; ++p) cw[p] = cayley_w[oi * 20 + p];
  __syncthreads();

  #pragma unroll
  for (int dl = 0; dl < 4; ++dl) {
    const int l = l0 + dl;
    #pragma unroll
    for (int m = 0; m < 8; ++m) {
      const int kk = TB.kk_idx[l][m];
      const int p = TB.pid[TB.grade[kk]][TB.grade[l]][TB.grade[m]];
      const float wv = (TB.kk_sgn[l][m] > 0) ? cw[p] : -cw[p];
      float* orow = out + ((size_t)((o * 8 + l) * 256 + i * 8 + m)) * 343;
      for (int c = tid; c < 343; c += 256) orow[c] = sk[c * 9 + kk] * wv;
    }
  }
}

extern "C" void kernel_launch(void* const* d_in, const int* in_sizes, int n_in,
                              void* d_out, int out_size, void* d_ws,
                              size_t ws_size, hipStream_t stream) {
  const float* condition     = (const float*)d_in[0];
  const float* rel_pos_sigma = (const float*)d_in[1];
  const float* cayley_w      = (const float*)d_in[2];
  const float* lin0_W        = (const float*)d_in[3];
  const float* lin0_b        = (const float*)d_in[4];
  const float* act0_a        = (const float*)d_in[5];
  const float* act0_b        = (const float*)d_in[6];
  const float* gps_w         = (const float*)d_in[7];
  const float* lins_W        = (const float*)d_in[8];
  const float* lins_b        = (const float*)d_in[9];
  const float* acts_a        = (const float*)d_in[10];
  const float* acts_b        = (const float*)d_in[11];
  const float* out_W         = (const float*)d_in[12];
  const float* out_b         = (const float*)d_in[13];
  const float* shell_sigma   = (const float*)d_in[14];

  float* ws = (float*)d_ws;
  float* kws = ws + OFF_KWS;
  float* hbuf = ws + OFF_HBUF;
  float* out = (float*)d_out;

  ccs_prep_kernel<<<dim3(640), dim3(256), 0, stream>>>(lin0_W, gps_w, out_W,
                                                       ws);
  ccs_net_kernel<<<dim3(343), dim3(256), 0, stream>>>(
      condition, rel_pos_sigma, lin0_b, act0_a, act0_b, lins_W, lins_b, acts_a,
      acts_b, ws, hbuf);
  ccs_out_kernel<<<dim3(4, 86), dim3(256), 0, stream>>>(out_b, shell_sigma, ws,
                                                        hbuf, kws);
  ccs_expand_kernel<<<dim3(1024, 2), dim3(256), 0, stream>>>(cayley_w, kws,
                                                             out);
}